// Round 20
// baseline (610.624 us; speedup 1.0000x reference)
//
#include <hip/hip_runtime.h>
#include <math.h>
#include <stdint.h>

// ---------------- problem constants ----------------
constexpr int BB   = 32;
constexpr int HW   = 3136;           // 56*56
constexpr int C0   = 256, C1 = 128, C2 = 64;
constexpr int NA   = 9;
constexpr int NCAND = HW * NA;       // 28224
constexpr int KSEL  = 1024;
constexpr int MAXDET = 100;

typedef _Float16 half8 __attribute__((ext_vector_type(8)));
typedef _Float16 half4v __attribute__((ext_vector_type(4)));
typedef float    f32x4  __attribute__((ext_vector_type(4)));
typedef float    f32x16 __attribute__((ext_vector_type(16)));

// ---------------- global -> LDS direct load (16B per lane) ----------------
__device__ __forceinline__ void g2l16(const void* g, void* l) {
    auto gp = reinterpret_cast<const __attribute__((address_space(1))) char*>(
        reinterpret_cast<uintptr_t>(g));
    auto lp = reinterpret_cast<__attribute__((address_space(3))) char*>(
        reinterpret_cast<uintptr_t>(l));
    __builtin_amdgcn_global_load_lds(gp, lp, 16, 0, 0);
}

// ---------------- merged prep: BN constants (both layers) ----------------
__global__ void bn_prep2(const float* g1, const float* be1, const float* m1,
                         const float* v1, const float* cb1,
                         const float* g2, const float* be2, const float* m2,
                         const float* v2, const float* cb2,
                         float* scl1, float* tb1, float* scl2, float* tb2) {
    int i = threadIdx.x;
    if (i < C1) {
        float inv = 1.f / sqrtf(v1[i] + 1e-5f);
        float s = g1[i] * inv;
        scl1[i] = s;
        tb1[i] = be1[i] + (cb1[i] - m1[i]) * s;
    }
    if (i < C2) {
        float inv = 1.f / sqrtf(v2[i] + 1e-5f);
        float s = g2[i] * inv;
        scl2[i] = s;
        tb2[i] = be2[i] + (cb2[i] - m2[i]) * s;
    }
}

// ---------------- merged weight reorder (both layers) ----------------
// layout out: [ch][plane][oc][32] halves, ch = cg*9 + r (r-inner), cin = cg*32+ci
__device__ __forceinline__ void reorder_one(const float* w, _Float16* wc,
                                            int i, int CIN, int COUT) {
    int K = CIN * 9;
    int ci  = i & 31;
    int row = (i >> 5) % (2 * COUT);
    int ch  = (i >> 5) / (2 * COUT);
    int pl  = row / COUT;
    int oc  = row - pl * COUT;
    int cg = ch / 9, r = ch - cg * 9;
    int cin = cg * 32 + ci;
    float v = w[oc * K + cin * 9 + r];
    _Float16 h = (_Float16)v;
    wc[i] = pl ? (_Float16)(v - (float)h) : h;
}

__global__ void reorder_w_both(const float* __restrict__ w1, _Float16* __restrict__ w1c,
                               const float* __restrict__ w2, _Float16* __restrict__ w2c) {
    constexpr int N1 = 2 * C1 * C0 * 9;     // 589824
    constexpr int N2 = 2 * C2 * C1 * 9;     // 147456
    int i = blockIdx.x * 256 + threadIdx.x;
    if (i < N1) reorder_one(w1, w1c, i, C0, C1);
    else if (i < N1 + N2) reorder_one(w2, w2c, i - N1, C1, C2);
}

// ---------------- NCHW fp32 -> NHWC fp16 hi/lo split (tiled transpose) ----------------
__global__ __launch_bounds__(256) void nchw_to_nhwc_split(
    const float* __restrict__ in, _Float16* __restrict__ hi, _Float16* __restrict__ lo)
{
    __shared__ float tile[64 * 68];
    const int pt = blockIdx.x * 64, ct = blockIdx.y * 64, b = blockIdx.z;
    const int t = threadIdx.x;
    const int r0 = t >> 4, cidx = (t & 15) * 4;
#pragma unroll
    for (int rr = 0; rr < 64; rr += 16) {
        int r = rr + r0;
        const float* src = in + ((size_t)(b * 256 + ct + r)) * HW + pt + cidx;
        float4 v = *(const float4*)src;
        float* d = &tile[r * 68 + cidx];
        d[0] = v.x; d[1] = v.y; d[2] = v.z; d[3] = v.w;
    }
    __syncthreads();
    const int p = t >> 2, c0 = (t & 3) * 16;
    size_t obase = ((size_t)(b * HW + pt + p)) * 256 + ct + c0;
    half8 h0, h1, l0, l1;
#pragma unroll
    for (int j = 0; j < 16; ++j) {
        float v = tile[(c0 + j) * 68 + p];
        _Float16 hh = (_Float16)v;
        _Float16 ll = (_Float16)(v - (float)hh);
        if (j < 8) { h0[j] = hh; l0[j] = ll; }
        else       { h1[j - 8] = hh; l1[j - 8] = ll; }
    }
    *(half8*)(hi + obase)     = h0;
    *(half8*)(hi + obase + 8) = h1;
    *(half8*)(lo + obase)     = l0;
    *(half8*)(lo + obase + 8) = l1;
}

// ---------------- conv1: dbuf + counted vmcnt + raw barriers + setprio ----------------
// r18-validated structure (225 -> 214.5 us). T5 setprio added: raw barriers
// leave waves phase-skewed (some staging ch+2 while others enter compute),
// so the CU scheduler has a role-split to arbitrate.
template <int CIN, int COUT, bool NHWC_OUT>
__global__ __launch_bounds__(256, 2) void conv3x3_v18(
    const _Float16* __restrict__ xhi,  // [B][3136][CIN] NHWC
    const _Float16* __restrict__ xlo,
    const _Float16* __restrict__ wc,   // [NCH][2][COUT][32]
    const _Float16* __restrict__ zbuf,
    const float* __restrict__ scl, const float* __restrict__ tb,
    _Float16* __restrict__ ohi, _Float16* __restrict__ olo,
    float* __restrict__ onchw)
{
    constexpr int K       = CIN * 9;
    constexpr int NCH     = K / 32;
    constexpr int WROWS   = 2 * COUT;
    constexpr int CHALVES = WROWS * 32;
    constexpr int WI      = WROWS / 64;        // conv1: 4 -> 8 g2l16/stage/wave
    constexpr int PI      = 2;
    constexpr int WOC     = COUT / 64;

    __shared__ __align__(16) _Float16 SP[2][128 * 64];
    __shared__ __align__(16) _Float16 SW[2][WROWS * 32];

    const int bid = blockIdx.x;
    const int swz = (bid & 7) * (gridDim.x >> 3) + (bid >> 3);
    const int b = swz / 25;
    const int pixBase = (swz - b * 25) * 128;
    const int bHW = b * HW;

    const int t = threadIdx.x, l = t & 63, w = t >> 6;

    const int cpix = (l & 7) ^ ((l >> 3) & 7);
    const int ppl = cpix >> 2, pq = cpix & 3;
    const _Float16* xsp = ppl ? xlo : xhi;
    int py[4], px[4];
    const _Float16* pbase[4];
#pragma unroll
    for (int i = 0; i < 4; ++i) {
        int p = w * 32 + i * 8 + (l >> 3);
        int pix = pixBase + p;
        py[i] = pix / 56; px[i] = pix - py[i] * 56;
        pbase[i] = xsp + (size_t)(bHW + pix) * CIN + pq * 8;
    }
    const _Float16* wbase = wc + ((size_t)(w * (WI * 16) + (l >> 2))) * 32 + (l & 3) * 8;

    const int wid = t >> 6;
    const int wp = wid & 1, wo = wid >> 1;
    const int lc = l & 31, lk = l >> 5;

    f32x16 acc[PI][WOC];
#pragma unroll
    for (int pi = 0; pi < PI; ++pi)
#pragma unroll
        for (int oi = 0; oi < WOC; ++oi) acc[pi][oi] = (f32x16)0.f;

    auto stage = [&](int ch, int buf) {
        int cg = ch / 9, r = ch - cg * 9;
        int ky = r / 3;
        int dy = ky - 1, dx = (r - ky * 3) - 1;
        int off = (dy * 56 + dx) * CIN + cg * 32;
#pragma unroll
        for (int i = 0; i < 4; ++i) {
            bool v = ((unsigned)(py[i] + dy) < 56u) && ((unsigned)(px[i] + dx) < 56u);
            const void* src = v ? (const void*)(pbase[i] + off) : (const void*)zbuf;
            g2l16(src, (void*)&SP[buf][w * 2048 + i * 512]);
        }
        const _Float16* wsrc = wbase + (size_t)ch * CHALVES;
#pragma unroll
        for (int j = 0; j < WI; ++j)
            g2l16((const void*)(wsrc + j * 512), (void*)&SW[buf][(w * WI + j) * 512]);
    };

    auto compute = [&](int buf) {
        __builtin_amdgcn_s_setprio(1);
#pragma unroll
        for (int ks = 0; ks < 2; ++ks) {
            half8 pb[PI][2];
#pragma unroll
            for (int pi = 0; pi < PI; ++pi) {
                int prw = wp * (PI * 32) + pi * 32 + lc;
                int key = prw & 7;
#pragma unroll
                for (int pl2 = 0; pl2 < 2; ++pl2) {
                    int c = pl2 * 4 + ks * 2 + lk;
                    pb[pi][pl2] = *(const half8*)&SP[buf][prw * 64 + ((c ^ key) << 3)];
                }
            }
            half8 wa[WOC][2];
#pragma unroll
            for (int oi = 0; oi < WOC; ++oi)
#pragma unroll
                for (int pl2 = 0; pl2 < 2; ++pl2) {
                    int row = pl2 * COUT + wo * (WOC * 32) + oi * 32 + lc;
                    int c = ks * 2 + lk;
                    wa[oi][pl2] = *(const half8*)&SW[buf][row * 32 + (c << 3)];
                }
#pragma unroll
            for (int pi = 0; pi < PI; ++pi)
#pragma unroll
                for (int oi = 0; oi < WOC; ++oi) {
                    acc[pi][oi] = __builtin_amdgcn_mfma_f32_32x32x16_f16(wa[oi][0], pb[pi][0], acc[pi][oi], 0, 0, 0);
                    acc[pi][oi] = __builtin_amdgcn_mfma_f32_32x32x16_f16(wa[oi][0], pb[pi][1], acc[pi][oi], 0, 0, 0);
                    acc[pi][oi] = __builtin_amdgcn_mfma_f32_32x32x16_f16(wa[oi][1], pb[pi][0], acc[pi][oi], 0, 0, 0);
                }
        }
        __builtin_amdgcn_s_setprio(0);
    };

    // ---- prologue: two stages in flight ----
    stage(0, 0);
    stage(1, 1);
    int cur = 0;
    for (int ch = 0; ch < NCH; ++ch) {
        if (ch + 1 < NCH) {
            asm volatile("s_waitcnt vmcnt(8)" ::: "memory");   // cur buffer's 8 done
        } else {
            asm volatile("s_waitcnt vmcnt(0)" ::: "memory");   // tail: drain all
        }
        __builtin_amdgcn_sched_barrier(0);                      // rule #18 fence
        __builtin_amdgcn_s_barrier();    // all waves' cur-buffer loads complete
        compute(cur);
        __builtin_amdgcn_s_barrier();    // all reads of cur done -> safe to reuse
        if (ch + 2 < NCH) stage(ch + 2, cur);
        cur ^= 1;
    }

    // ---- epilogue ----
#pragma unroll
    for (int pi = 0; pi < PI; ++pi) {
        const int pix = pixBase + wp * (PI * 32) + pi * 32 + lc;
        if (pix < HW) {
#pragma unroll
            for (int oi = 0; oi < WOC; ++oi) {
#pragma unroll
                for (int g = 0; g < 4; ++g) {
                    const int oc0 = wo * (WOC * 32) + oi * 32 + 8 * g + 4 * lk;
                    f32x4 s4 = *(const f32x4*)(scl + oc0);
                    f32x4 t4 = *(const f32x4*)(tb + oc0);
                    if constexpr (NHWC_OUT) {
                        half4v hh, ll;
#pragma unroll
                        for (int m2 = 0; m2 < 4; ++m2) {
                            float val = fmaxf(acc[pi][oi][g * 4 + m2] * s4[m2] + t4[m2], 0.f);
                            _Float16 h = (_Float16)val;
                            hh[m2] = h;
                            ll[m2] = (_Float16)(val - (float)h);
                        }
                        size_t o = ((size_t)(bHW + pix)) * COUT + oc0;
                        *(half4v*)(ohi + o) = hh;
                        *(half4v*)(olo + o) = ll;
                    } else {
#pragma unroll
                        for (int m2 = 0; m2 < 4; ++m2) {
                            float val = fmaxf(acc[pi][oi][g * 4 + m2] * s4[m2] + t4[m2], 0.f);
                            onchw[((size_t)(b * COUT + oc0 + m2)) * HW + pix] = val;
                        }
                    }
                }
            }
        }
    }
}

// ---------------- conv2: proven v12 single-buffered structure (MINW=4) ----------------
template <int CIN, int COUT, int MINW, bool NHWC_OUT>
__global__ __launch_bounds__(256, MINW) void conv3x3_v12(
    const _Float16* __restrict__ xhi,
    const _Float16* __restrict__ xlo,
    const _Float16* __restrict__ wc,
    const _Float16* __restrict__ zbuf,
    const float* __restrict__ scl, const float* __restrict__ tb,
    _Float16* __restrict__ ohi, _Float16* __restrict__ olo,
    float* __restrict__ onchw)
{
    constexpr int K       = CIN * 9;
    constexpr int NCH     = K / 32;
    constexpr int WROWS   = 2 * COUT;
    constexpr int CHALVES = WROWS * 32;
    constexpr int WI      = WROWS / 64;
    constexpr int PI      = 2;
    constexpr int WOC     = COUT / 64;

    __shared__ __align__(16) _Float16 SP[128 * 64];
    __shared__ __align__(16) _Float16 SW[WROWS * 32];

    const int bid = blockIdx.x;
    const int swz = (bid & 7) * (gridDim.x >> 3) + (bid >> 3);
    const int b = swz / 25;
    const int pixBase = (swz - b * 25) * 128;
    const int bHW = b * HW;

    const int t = threadIdx.x, l = t & 63, w = t >> 6;

    const int cpix = (l & 7) ^ ((l >> 3) & 7);
    const int ppl = cpix >> 2, pq = cpix & 3;
    const _Float16* xsp = ppl ? xlo : xhi;
    int py[4], px[4];
    const _Float16* pbase[4];
#pragma unroll
    for (int i = 0; i < 4; ++i) {
        int p = w * 32 + i * 8 + (l >> 3);
        int pix = pixBase + p;
        py[i] = pix / 56; px[i] = pix - py[i] * 56;
        pbase[i] = xsp + (size_t)(bHW + pix) * CIN + pq * 8;
    }
    const _Float16* wbase = wc + ((size_t)(w * (WI * 16) + (l >> 2))) * 32 + (l & 3) * 8;

    const int wid = t >> 6;
    const int wp = wid & 1, wo = wid >> 1;
    const int lc = l & 31, lk = l >> 5;

    f32x16 acc[PI][WOC];
#pragma unroll
    for (int pi = 0; pi < PI; ++pi)
#pragma unroll
        for (int oi = 0; oi < WOC; ++oi) acc[pi][oi] = (f32x16)0.f;

    auto stage = [&](int ch) {
        int cg = ch / 9, r = ch - cg * 9;
        int ky = r / 3;
        int dy = ky - 1, dx = (r - ky * 3) - 1;
        int off = (dy * 56 + dx) * CIN + cg * 32;
#pragma unroll
        for (int i = 0; i < 4; ++i) {
            bool v = ((unsigned)(py[i] + dy) < 56u) && ((unsigned)(px[i] + dx) < 56u);
            const void* src = v ? (const void*)(pbase[i] + off) : (const void*)zbuf;
            g2l16(src, (void*)&SP[w * 2048 + i * 512]);
        }
        const _Float16* wsrc = wbase + (size_t)ch * CHALVES;
#pragma unroll
        for (int j = 0; j < WI; ++j)
            g2l16((const void*)(wsrc + j * 512), (void*)&SW[(w * WI + j) * 512]);
    };

    auto compute = [&]() {
#pragma unroll
        for (int ks = 0; ks < 2; ++ks) {
            half8 pb[PI][2];
#pragma unroll
            for (int pi = 0; pi < PI; ++pi) {
                int prw = wp * (PI * 32) + pi * 32 + lc;
                int key = prw & 7;
#pragma unroll
                for (int pl2 = 0; pl2 < 2; ++pl2) {
                    int c = pl2 * 4 + ks * 2 + lk;
                    pb[pi][pl2] = *(const half8*)&SP[prw * 64 + ((c ^ key) << 3)];
                }
            }
            half8 wa[WOC][2];
#pragma unroll
            for (int oi = 0; oi < WOC; ++oi)
#pragma unroll
                for (int pl2 = 0; pl2 < 2; ++pl2) {
                    int row = pl2 * COUT + wo * (WOC * 32) + oi * 32 + lc;
                    int c = ks * 2 + lk;
                    wa[oi][pl2] = *(const half8*)&SW[row * 32 + (c << 3)];
                }
#pragma unroll
            for (int pi = 0; pi < PI; ++pi)
#pragma unroll
                for (int oi = 0; oi < WOC; ++oi) {
                    acc[pi][oi] = __builtin_amdgcn_mfma_f32_32x32x16_f16(wa[oi][0], pb[pi][0], acc[pi][oi], 0, 0, 0);
                    acc[pi][oi] = __builtin_amdgcn_mfma_f32_32x32x16_f16(wa[oi][0], pb[pi][1], acc[pi][oi], 0, 0, 0);
                    acc[pi][oi] = __builtin_amdgcn_mfma_f32_32x32x16_f16(wa[oi][1], pb[pi][0], acc[pi][oi], 0, 0, 0);
                }
        }
    };

    for (int ch = 0; ch < NCH; ++ch) {
        stage(ch);
        __syncthreads();
        compute();
        __syncthreads();
    }

#pragma unroll
    for (int pi = 0; pi < PI; ++pi) {
        const int pix = pixBase + wp * (PI * 32) + pi * 32 + lc;
        if (pix < HW) {
#pragma unroll
            for (int oi = 0; oi < WOC; ++oi) {
#pragma unroll
                for (int g = 0; g < 4; ++g) {
                    const int oc0 = wo * (WOC * 32) + oi * 32 + 8 * g + 4 * lk;
                    f32x4 s4 = *(const f32x4*)(scl + oc0);
                    f32x4 t4 = *(const f32x4*)(tb + oc0);
                    if constexpr (NHWC_OUT) {
                        half4v hh, ll;
#pragma unroll
                        for (int m2 = 0; m2 < 4; ++m2) {
                            float val = fmaxf(acc[pi][oi][g * 4 + m2] * s4[m2] + t4[m2], 0.f);
                            _Float16 h = (_Float16)val;
                            hh[m2] = h;
                            ll[m2] = (_Float16)(val - (float)h);
                        }
                        size_t o = ((size_t)(bHW + pix)) * COUT + oc0;
                        *(half4v*)(ohi + o) = hh;
                        *(half4v*)(olo + o) = ll;
                    } else {
#pragma unroll
                        for (int m2 = 0; m2 < 4; ++m2) {
                            float val = fmaxf(acc[pi][oi][g * 4 + m2] * s4[m2] + t4[m2], 0.f);
                            onchw[((size_t)(b * COUT + oc0 + m2)) * HW + pix] = val;
                        }
                    }
                }
            }
        }
    }
}

// ---------------- conv1x1 (64 -> per-anchor 5) + decode (NCHW fp32 x2) ----------------
__global__ __launch_bounds__(256) void conv1x1_decode(
    const float* __restrict__ x2, const float* __restrict__ wo,
    const float* __restrict__ bo,
    float* __restrict__ boxes, float* __restrict__ scores)
{
    __shared__ float ws[64 * 56];
    for (int i = threadIdx.x; i < 54 * 64; i += 256) {
        int oc = i % 54, c = i / 54;
        ws[c * 56 + oc] = wo[oc * 64 + c];
    }
    __syncthreads();

    int u = blockIdx.x * 256 + threadIdx.x;
    int a = u % 9;
    int rest = u / 9;
    int quad = rest % 784;
    int b = rest / 784;
    int pix0 = quad * 4;
    int y = pix0 / 56;
    int x0 = pix0 - y * 56;

    const float* xb = x2 + (size_t)b * 64 * HW + pix0;
    float acc[5][4];
#pragma unroll
    for (int j = 0; j < 5; ++j)
#pragma unroll
        for (int p = 0; p < 4; ++p) acc[j][p] = 0.f;

#pragma unroll 8
    for (int c = 0; c < 64; ++c) {
        float4 xv = *(const float4*)(xb + c * HW);
#pragma unroll
        for (int j = 0; j < 5; ++j) {
            float w = ws[c * 56 + a * 6 + j];
            acc[j][0] += w * xv.x;
            acc[j][1] += w * xv.y;
            acc[j][2] += w * xv.z;
            acc[j][3] += w * xv.w;
        }
    }

    int si = a / 3, ri = a - si * 3;
    float sv = (float)(32 << si);
    float rv = 0.5f * (float)(1 << ri);
    float aw = (sv * rv) / 224.f;
    float ah = (sv / rv) / 224.f;
    float bo0 = bo[a * 6 + 0], bo1 = bo[a * 6 + 1], bo2 = bo[a * 6 + 2];
    float bo3 = bo[a * 6 + 3], bo4 = bo[a * 6 + 4];

#pragma unroll
    for (int p = 0; p < 4; ++p) {
        float p0 = acc[0][p] + bo0;
        float p1 = acc[1][p] + bo1;
        float p2 = acc[2][p] + bo2;
        float p3 = acc[3][p] + bo3;
        float p4 = acc[4][p] + bo4;
        float sx = 1.f / (1.f + expf(-p0));
        float sy = 1.f / (1.f + expf(-p1));
        float pxc = (sx + (float)(x0 + p)) / 56.f;
        float pyc = (sy + (float)y) / 56.f;
        float pw = expf(p2) * aw;
        float ph = expf(p3) * ah;
        float sc = 1.f / (1.f + expf(-p4));
        int n = (y * 56 + x0 + p) * 9 + a;
        float4 bx; bx.x = pxc; bx.y = pyc; bx.z = pw; bx.w = ph;
        *(float4*)&boxes[((size_t)b * NCAND + n) * 4] = bx;
        scores[(size_t)b * NCAND + n] = sc;
    }
}

// ---------------- top-K v3: 3 radix rounds (11/10/10 bits), parallel scan ----------------
__device__ __forceinline__ unsigned fkey(float f) {
    unsigned u = __float_as_uint(f);
    return (u & 0x80000000u) ? ~u : (u | 0x80000000u);
}

__global__ __launch_bounds__(1024) void topk_select(
    const float* __restrict__ scores, const float* __restrict__ boxes,
    float* __restrict__ cbox, float* __restrict__ csc, int* __restrict__ cidx)
{
    const int b = blockIdx.x, t = threadIdx.x;
    const float* sp = scores + (size_t)b * NCAND;
    const int lane = t & 63, w = t >> 6;

    __shared__ unsigned hist[2048];
    __shared__ unsigned gsum[64];
    __shared__ unsigned wsum[16];
    __shared__ unsigned s_sel, s_need, s_tot0, s_tot1;

    unsigned prefix = 0x80000000u, maskSo = 0x80000000u;
    int need = KSEL;

    for (int round = 0; round < 3; ++round) {
        const int shift = (round == 0) ? 20 : (round == 1 ? 10 : 0);
        const unsigned bmask = (round == 0) ? 2047u : 1023u;
        const int ngroups = (round == 0) ? 64 : 32;

        hist[t] = 0;
        if (round == 0) hist[t + 1024] = 0;
        __syncthreads();
        for (int i = t; i < NCAND; i += 1024) {
            unsigned u = fkey(sp[i]);
            if ((u & maskSo) == prefix) atomicAdd(&hist[(u >> shift) & bmask], 1u);
        }
        __syncthreads();
        if (t < ngroups) {
            unsigned s = 0;
#pragma unroll 8
            for (int k = 0; k < 32; ++k) s += hist[t * 32 + k];
            gsum[t] = s;
        }
        __syncthreads();
        if (t == 0) {
            int rem = need;
            int g = ngroups - 1;
            for (;; --g) {
                if ((int)gsum[g] >= rem || g == 0) break;
                rem -= (int)gsum[g];
            }
            unsigned sel = (unsigned)(g * 32);
            for (int v = g * 32 + 31; v >= g * 32; --v) {
                int c = (int)hist[v];
                if (c >= rem || v == g * 32) { sel = (unsigned)v; break; }
                rem -= c;
            }
            s_sel = sel; s_need = (unsigned)rem;
        }
        __syncthreads();
        prefix |= (s_sel << shift);
        maskSo |= (bmask << shift);
        need = (int)s_need;
        __syncthreads();
    }

    const unsigned cutoff = prefix;
    const unsigned needT = (unsigned)need;
    unsigned outBase = 0, tieBase = 0;
    const unsigned long long mlt = (1ull << lane) - 1ull;

    for (int c0 = 0; c0 < NCAND; c0 += 1024) {
        int i = c0 + t;
        bool valid = i < NCAND;
        float sc = valid ? sp[i] : 0.f;
        unsigned u = valid ? fkey(sc) : 0u;
        bool gt = valid && (u > cutoff);
        bool eq = valid && (u == cutoff);

        unsigned long long balE = __ballot(eq);
        unsigned lpE = (unsigned)__popcll(balE & mlt);
        if (lane == 0) wsum[w] = (unsigned)__popcll(balE);
        __syncthreads();
        if (t == 0) {
            unsigned run = 0;
            for (int k = 0; k < 16; ++k) { unsigned x = wsum[k]; wsum[k] = run; run += x; }
            s_tot1 = run;
        }
        __syncthreads();
        unsigned tieRank = tieBase + wsum[w] + lpE;
        bool take = gt || (eq && tieRank < needT);
        __syncthreads();

        unsigned long long balT = __ballot(take);
        unsigned lpT = (unsigned)__popcll(balT & mlt);
        if (lane == 0) wsum[w] = (unsigned)__popcll(balT);
        __syncthreads();
        if (t == 0) {
            unsigned run = 0;
            for (int k = 0; k < 16; ++k) { unsigned x = wsum[k]; wsum[k] = run; run += x; }
            s_tot0 = run;
        }
        __syncthreads();
        unsigned pos = outBase + wsum[w] + lpT;
        if (take) {
            float4 bx = *(const float4*)&boxes[((size_t)b * NCAND + i) * 4];
            *(float4*)&cbox[((size_t)b * KSEL + pos) * 4] = bx;
            csc[(size_t)b * KSEL + pos] = sc;
            cidx[(size_t)b * KSEL + pos] = i;
        }
        tieBase += s_tot1;
        outBase += s_tot0;
        __syncthreads();
    }
}

// ---------------- NMS: one wave per image, all candidates in registers ----------------
__global__ __launch_bounds__(64) void nms_wave(
    const float* __restrict__ cbox, const float* __restrict__ csc,
    const int* __restrict__ cidx, float* __restrict__ out)
{
    const int b = blockIdx.x, l = threadIdx.x;
    float cx[16], cy[16], w_[16], h_[16], s[16];
    int id[16];
#pragma unroll
    for (int j = 0; j < 16; ++j) {
        int ci = (b << 10) + (j << 6) + l;
        float4 bb = *(const float4*)&cbox[(size_t)ci * 4];
        float sc = csc[ci];
        cx[j] = bb.x; cy[j] = bb.y; w_[j] = bb.z; h_[j] = bb.w;
        s[j] = sc > 0.3f ? sc : -1.f;
        id[j] = cidx[ci];
    }
    float* ob = out + (size_t)b * MAXDET * 4;

    for (int it = 0; it < MAXDET; ++it) {
        float bs = s[0]; int bi = id[0];
        float bcx = cx[0], bcy = cy[0], bw = w_[0], bh = h_[0];
#pragma unroll
        for (int j = 1; j < 16; ++j) {
            bool tk = (s[j] > bs) || (s[j] == bs && id[j] < bi);
            if (tk) { bs = s[j]; bi = id[j]; bcx = cx[j]; bcy = cy[j]; bw = w_[j]; bh = h_[j]; }
        }
#pragma unroll
        for (int m2 = 1; m2 < 64; m2 <<= 1) {
            float os = __shfl_xor(bs, m2); int oi = __shfl_xor(bi, m2);
            float ox = __shfl_xor(bcx, m2), oy = __shfl_xor(bcy, m2);
            float ow = __shfl_xor(bw, m2), oh2 = __shfl_xor(bh, m2);
            bool tk = (os > bs) || (os == bs && oi < bi);
            if (tk) { bs = os; bi = oi; bcx = ox; bcy = oy; bw = ow; bh = oh2; }
        }
        if (bs <= 0.f) {
            for (int q = it * 4 + l; q < MAXDET * 4; q += 64) ob[q] = 0.f;
            break;
        }
        if (l == 0) {
            float4 o; o.x = bcx; o.y = bcy; o.z = bw; o.w = bh;
            *(float4*)&ob[it * 4] = o;
        }
        float wx1 = bcx - bw / 2.f, wy1 = bcy - bh / 2.f;
        float wx2 = bcx + bw / 2.f, wy2 = bcy + bh / 2.f;
        float war = (wx2 - wx1) * (wy2 - wy1);
#pragma unroll
        for (int j = 0; j < 16; ++j) {
            float jx1 = cx[j] - w_[j] / 2.f, jy1 = cy[j] - h_[j] / 2.f;
            float jx2 = cx[j] + w_[j] / 2.f, jy2 = cy[j] + h_[j] / 2.f;
            float iw = fminf(wx2, jx2) - fmaxf(wx1, jx1); iw = fmaxf(iw, 0.f);
            float ih = fminf(wy2, jy2) - fmaxf(wy1, jy1); ih = fmaxf(ih, 0.f);
            float inter = iw * ih;
            float jar = (jx2 - jx1) * (jy2 - jy1);
            float uni = war + jar - inter;
            if (inter / (uni + 1e-16f) > 0.2f) s[j] = -1.f;
        }
    }
}

// ---------------- host launcher ----------------
extern "C" void kernel_launch(void* const* d_in, const int* in_sizes, int n_in,
                              void* d_out, int out_size, void* d_ws, size_t ws_size,
                              hipStream_t stream)
{
    const float* features = (const float*)d_in[0];
    const float* w1 = (const float*)d_in[1];
    const float* b1 = (const float*)d_in[2];
    const float* g1 = (const float*)d_in[3];
    const float* be1 = (const float*)d_in[4];
    const float* m1 = (const float*)d_in[5];
    const float* v1 = (const float*)d_in[6];
    const float* w2 = (const float*)d_in[7];
    const float* b2 = (const float*)d_in[8];
    const float* g2 = (const float*)d_in[9];
    const float* be2 = (const float*)d_in[10];
    const float* m2 = (const float*)d_in[11];
    const float* v2 = (const float*)d_in[12];
    const float* wo = (const float*)d_in[13];
    const float* bo = (const float*)d_in[14];

    char* ws = (char*)d_ws;
    size_t off = 0;
    auto alloc = [&](size_t bytes) {
        char* p = ws + off;
        off += (bytes + 255) / 256 * 256;
        return p;
    };

    _Float16* zbuf = (_Float16*)alloc(256);
    _Float16* w1c = (_Float16*)alloc((size_t)2 * C1 * 2304 * 2);
    _Float16* w2c = (_Float16*)alloc((size_t)2 * C2 * 1152 * 2);
    float* scl1 = (float*)alloc(C1 * 4);
    float* tb1  = (float*)alloc(C1 * 4);
    float* scl2 = (float*)alloc(C2 * 4);
    float* tb2  = (float*)alloc(C2 * 4);

    // Region B: fhi/flo (dead after conv1), then reused for x2/boxes/scores
    const size_t planeF = (size_t)BB * HW * C0 * 2;    // 51,380,224
    char* regB = alloc(2 * planeF);
    _Float16* fhi = (_Float16*)regB;
    _Float16* flo = (_Float16*)(regB + planeF);

    // Region C: x1 hi/lo (dead after conv2), then reused for cbox/csc/cidx
    const size_t planeX1 = (size_t)BB * HW * C1 * 2;   // 25,690,112
    char* regC = alloc(2 * planeX1);
    _Float16* x1hi = (_Float16*)regC;
    _Float16* x1lo = (_Float16*)(regC + planeX1);

    // aliases into region B (valid after conv1 completes)
    float* x2     = (float*)regB;
    float* boxes  = (float*)(regB + 25690112);
    float* scores = (float*)(regB + 25690112 + 14450688);
    // aliases into region C (valid after conv2 completes)
    float* cbox = (float*)regC;
    float* csc  = (float*)(regC + 524288);
    int*   cidx = (int*)(regC + 524288 + 131072);

    hipMemsetAsync(zbuf, 0, 256, stream);
    bn_prep2<<<1, 256, 0, stream>>>(g1, be1, m1, v1, b1, g2, be2, m2, v2, b2,
                                    scl1, tb1, scl2, tb2);
    {
        int total = 2 * C1 * 2304 + 2 * C2 * 1152;
        reorder_w_both<<<(total + 255) / 256, 256, 0, stream>>>(w1, w1c, w2, w2c);
    }

    nchw_to_nhwc_split<<<dim3(49, 4, BB), 256, 0, stream>>>(features, fhi, flo);

    conv3x3_v18<C0, C1, true><<<800, 256, 0, stream>>>(
        fhi, flo, w1c, zbuf, scl1, tb1, x1hi, x1lo, nullptr);
    conv3x3_v12<C1, C2, 4, false><<<800, 256, 0, stream>>>(
        x1hi, x1lo, w2c, zbuf, scl2, tb2, nullptr, nullptr, x2);

    conv1x1_decode<<<(BB * 784 * NA) / 256, 256, 0, stream>>>(x2, wo, bo, boxes, scores);

    topk_select<<<BB, 1024, 0, stream>>>(scores, boxes, cbox, csc, cidx);
    nms_wave<<<BB, 64, 0, stream>>>(cbox, csc, cidx, (float*)d_out);
}

// Round 21
// 592.945 us; speedup vs baseline: 1.0298x; 1.0298x over previous
//
#include <hip/hip_runtime.h>
#include <math.h>
#include <stdint.h>

// ---------------- problem constants ----------------
constexpr int BB   = 32;
constexpr int HW   = 3136;           // 56*56
constexpr int C0   = 256, C1 = 128, C2 = 64;
constexpr int NA   = 9;
constexpr int NCAND = HW * NA;       // 28224
constexpr int KSEL  = 1024;
constexpr int MAXDET = 100;

typedef _Float16 half8 __attribute__((ext_vector_type(8)));
typedef _Float16 half4v __attribute__((ext_vector_type(4)));
typedef float    f32x4  __attribute__((ext_vector_type(4)));
typedef float    f32x16 __attribute__((ext_vector_type(16)));

// ---------------- global -> LDS direct load (16B per lane) ----------------
__device__ __forceinline__ void g2l16(const void* g, void* l) {
    auto gp = reinterpret_cast<const __attribute__((address_space(1))) char*>(
        reinterpret_cast<uintptr_t>(g));
    auto lp = reinterpret_cast<__attribute__((address_space(3))) char*>(
        reinterpret_cast<uintptr_t>(l));
    __builtin_amdgcn_global_load_lds(gp, lp, 16, 0, 0);
}

// ---------------- merged prep: BN constants (both layers) ----------------
__global__ void bn_prep2(const float* g1, const float* be1, const float* m1,
                         const float* v1, const float* cb1,
                         const float* g2, const float* be2, const float* m2,
                         const float* v2, const float* cb2,
                         float* scl1, float* tb1, float* scl2, float* tb2) {
    int i = threadIdx.x;
    if (i < C1) {
        float inv = 1.f / sqrtf(v1[i] + 1e-5f);
        float s = g1[i] * inv;
        scl1[i] = s;
        tb1[i] = be1[i] + (cb1[i] - m1[i]) * s;
    }
    if (i < C2) {
        float inv = 1.f / sqrtf(v2[i] + 1e-5f);
        float s = g2[i] * inv;
        scl2[i] = s;
        tb2[i] = be2[i] + (cb2[i] - m2[i]) * s;
    }
}

// ---------------- merged weight reorder (both layers) ----------------
// layout out: [ch][plane][oc][32] halves, ch = cg*9 + r (r-inner), cin = cg*32+ci
__device__ __forceinline__ void reorder_one(const float* w, _Float16* wc,
                                            int i, int CIN, int COUT) {
    int K = CIN * 9;
    int ci  = i & 31;
    int row = (i >> 5) % (2 * COUT);
    int ch  = (i >> 5) / (2 * COUT);
    int pl  = row / COUT;
    int oc  = row - pl * COUT;
    int cg = ch / 9, r = ch - cg * 9;
    int cin = cg * 32 + ci;
    float v = w[oc * K + cin * 9 + r];
    _Float16 h = (_Float16)v;
    wc[i] = pl ? (_Float16)(v - (float)h) : h;
}

__global__ void reorder_w_both(const float* __restrict__ w1, _Float16* __restrict__ w1c,
                               const float* __restrict__ w2, _Float16* __restrict__ w2c) {
    constexpr int N1 = 2 * C1 * C0 * 9;     // 589824
    constexpr int N2 = 2 * C2 * C1 * 9;     // 147456
    int i = blockIdx.x * 256 + threadIdx.x;
    if (i < N1) reorder_one(w1, w1c, i, C0, C1);
    else if (i < N1 + N2) reorder_one(w2, w2c, i - N1, C1, C2);
}

// ---------------- NCHW fp32 -> NHWC fp16 hi/lo split (tiled transpose) ----------------
__global__ __launch_bounds__(256) void nchw_to_nhwc_split(
    const float* __restrict__ in, _Float16* __restrict__ hi, _Float16* __restrict__ lo)
{
    __shared__ float tile[64 * 68];
    const int pt = blockIdx.x * 64, ct = blockIdx.y * 64, b = blockIdx.z;
    const int t = threadIdx.x;
    const int r0 = t >> 4, cidx = (t & 15) * 4;
#pragma unroll
    for (int rr = 0; rr < 64; rr += 16) {
        int r = rr + r0;
        const float* src = in + ((size_t)(b * 256 + ct + r)) * HW + pt + cidx;
        float4 v = *(const float4*)src;
        float* d = &tile[r * 68 + cidx];
        d[0] = v.x; d[1] = v.y; d[2] = v.z; d[3] = v.w;
    }
    __syncthreads();
    const int p = t >> 2, c0 = (t & 3) * 16;
    size_t obase = ((size_t)(b * HW + pt + p)) * 256 + ct + c0;
    half8 h0, h1, l0, l1;
#pragma unroll
    for (int j = 0; j < 16; ++j) {
        float v = tile[(c0 + j) * 68 + p];
        _Float16 hh = (_Float16)v;
        _Float16 ll = (_Float16)(v - (float)hh);
        if (j < 8) { h0[j] = hh; l0[j] = ll; }
        else       { h1[j - 8] = hh; l1[j - 8] = ll; }
    }
    *(half8*)(hi + obase)     = h0;
    *(half8*)(hi + obase + 8) = h1;
    *(half8*)(lo + obase)     = l0;
    *(half8*)(lo + obase + 8) = l1;
}

// ---------------- conv1: dbuf + counted vmcnt + raw barriers (r18 best) ----------------
// Per stage: exactly 8 g2l16/wave (4 pix + 4 wt). Loop keeps the NEXT buffer's
// 8 loads in flight across both raw barriers; s_waitcnt vmcnt(8) retires only
// the CURRENT buffer's loads. Measured r18: conv1 225 -> 214.5 us. NO setprio
// (r20 showed it starves co-resident staging waves at 2 blocks/CU: -25 us).
template <int CIN, int COUT, bool NHWC_OUT>
__global__ __launch_bounds__(256, 2) void conv3x3_v18(
    const _Float16* __restrict__ xhi,  // [B][3136][CIN] NHWC
    const _Float16* __restrict__ xlo,
    const _Float16* __restrict__ wc,   // [NCH][2][COUT][32]
    const _Float16* __restrict__ zbuf,
    const float* __restrict__ scl, const float* __restrict__ tb,
    _Float16* __restrict__ ohi, _Float16* __restrict__ olo,
    float* __restrict__ onchw)
{
    constexpr int K       = CIN * 9;
    constexpr int NCH     = K / 32;
    constexpr int WROWS   = 2 * COUT;
    constexpr int CHALVES = WROWS * 32;
    constexpr int WI      = WROWS / 64;        // conv1: 4 -> 8 g2l16/stage/wave
    constexpr int PI      = 2;
    constexpr int WOC     = COUT / 64;

    __shared__ __align__(16) _Float16 SP[2][128 * 64];
    __shared__ __align__(16) _Float16 SW[2][WROWS * 32];

    const int bid = blockIdx.x;
    const int swz = (bid & 7) * (gridDim.x >> 3) + (bid >> 3);
    const int b = swz / 25;
    const int pixBase = (swz - b * 25) * 128;
    const int bHW = b * HW;

    const int t = threadIdx.x, l = t & 63, w = t >> 6;

    const int cpix = (l & 7) ^ ((l >> 3) & 7);
    const int ppl = cpix >> 2, pq = cpix & 3;
    const _Float16* xsp = ppl ? xlo : xhi;
    int py[4], px[4];
    const _Float16* pbase[4];
#pragma unroll
    for (int i = 0; i < 4; ++i) {
        int p = w * 32 + i * 8 + (l >> 3);
        int pix = pixBase + p;
        py[i] = pix / 56; px[i] = pix - py[i] * 56;
        pbase[i] = xsp + (size_t)(bHW + pix) * CIN + pq * 8;
    }
    const _Float16* wbase = wc + ((size_t)(w * (WI * 16) + (l >> 2))) * 32 + (l & 3) * 8;

    const int wid = t >> 6;
    const int wp = wid & 1, wo = wid >> 1;
    const int lc = l & 31, lk = l >> 5;

    f32x16 acc[PI][WOC];
#pragma unroll
    for (int pi = 0; pi < PI; ++pi)
#pragma unroll
        for (int oi = 0; oi < WOC; ++oi) acc[pi][oi] = (f32x16)0.f;

    auto stage = [&](int ch, int buf) {
        int cg = ch / 9, r = ch - cg * 9;
        int ky = r / 3;
        int dy = ky - 1, dx = (r - ky * 3) - 1;
        int off = (dy * 56 + dx) * CIN + cg * 32;
#pragma unroll
        for (int i = 0; i < 4; ++i) {
            bool v = ((unsigned)(py[i] + dy) < 56u) && ((unsigned)(px[i] + dx) < 56u);
            const void* src = v ? (const void*)(pbase[i] + off) : (const void*)zbuf;
            g2l16(src, (void*)&SP[buf][w * 2048 + i * 512]);
        }
        const _Float16* wsrc = wbase + (size_t)ch * CHALVES;
#pragma unroll
        for (int j = 0; j < WI; ++j)
            g2l16((const void*)(wsrc + j * 512), (void*)&SW[buf][(w * WI + j) * 512]);
    };

    auto compute = [&](int buf) {
#pragma unroll
        for (int ks = 0; ks < 2; ++ks) {
            half8 pb[PI][2];
#pragma unroll
            for (int pi = 0; pi < PI; ++pi) {
                int prw = wp * (PI * 32) + pi * 32 + lc;
                int key = prw & 7;
#pragma unroll
                for (int pl2 = 0; pl2 < 2; ++pl2) {
                    int c = pl2 * 4 + ks * 2 + lk;
                    pb[pi][pl2] = *(const half8*)&SP[buf][prw * 64 + ((c ^ key) << 3)];
                }
            }
            half8 wa[WOC][2];
#pragma unroll
            for (int oi = 0; oi < WOC; ++oi)
#pragma unroll
                for (int pl2 = 0; pl2 < 2; ++pl2) {
                    int row = pl2 * COUT + wo * (WOC * 32) + oi * 32 + lc;
                    int c = ks * 2 + lk;
                    wa[oi][pl2] = *(const half8*)&SW[buf][row * 32 + (c << 3)];
                }
#pragma unroll
            for (int pi = 0; pi < PI; ++pi)
#pragma unroll
                for (int oi = 0; oi < WOC; ++oi) {
                    acc[pi][oi] = __builtin_amdgcn_mfma_f32_32x32x16_f16(wa[oi][0], pb[pi][0], acc[pi][oi], 0, 0, 0);
                    acc[pi][oi] = __builtin_amdgcn_mfma_f32_32x32x16_f16(wa[oi][0], pb[pi][1], acc[pi][oi], 0, 0, 0);
                    acc[pi][oi] = __builtin_amdgcn_mfma_f32_32x32x16_f16(wa[oi][1], pb[pi][0], acc[pi][oi], 0, 0, 0);
                }
        }
    };

    // ---- prologue: two stages in flight ----
    stage(0, 0);
    stage(1, 1);
    int cur = 0;
    for (int ch = 0; ch < NCH; ++ch) {
        if (ch + 1 < NCH) {
            asm volatile("s_waitcnt vmcnt(8)" ::: "memory");   // cur buffer's 8 done
        } else {
            asm volatile("s_waitcnt vmcnt(0)" ::: "memory");   // tail: drain all
        }
        __builtin_amdgcn_sched_barrier(0);                      // rule #18 fence
        __builtin_amdgcn_s_barrier();    // all waves' cur-buffer loads complete
        compute(cur);
        __builtin_amdgcn_s_barrier();    // all reads of cur done -> safe to reuse
        if (ch + 2 < NCH) stage(ch + 2, cur);
        cur ^= 1;
    }

    // ---- epilogue ----
#pragma unroll
    for (int pi = 0; pi < PI; ++pi) {
        const int pix = pixBase + wp * (PI * 32) + pi * 32 + lc;
        if (pix < HW) {
#pragma unroll
            for (int oi = 0; oi < WOC; ++oi) {
#pragma unroll
                for (int g = 0; g < 4; ++g) {
                    const int oc0 = wo * (WOC * 32) + oi * 32 + 8 * g + 4 * lk;
                    f32x4 s4 = *(const f32x4*)(scl + oc0);
                    f32x4 t4 = *(const f32x4*)(tb + oc0);
                    if constexpr (NHWC_OUT) {
                        half4v hh, ll;
#pragma unroll
                        for (int m2 = 0; m2 < 4; ++m2) {
                            float val = fmaxf(acc[pi][oi][g * 4 + m2] * s4[m2] + t4[m2], 0.f);
                            _Float16 h = (_Float16)val;
                            hh[m2] = h;
                            ll[m2] = (_Float16)(val - (float)h);
                        }
                        size_t o = ((size_t)(bHW + pix)) * COUT + oc0;
                        *(half4v*)(ohi + o) = hh;
                        *(half4v*)(olo + o) = ll;
                    } else {
#pragma unroll
                        for (int m2 = 0; m2 < 4; ++m2) {
                            float val = fmaxf(acc[pi][oi][g * 4 + m2] * s4[m2] + t4[m2], 0.f);
                            onchw[((size_t)(b * COUT + oc0 + m2)) * HW + pix] = val;
                        }
                    }
                }
            }
        }
    }
}

// ---------------- conv2: proven v12 single-buffered structure (MINW=4) ----------------
template <int CIN, int COUT, int MINW, bool NHWC_OUT>
__global__ __launch_bounds__(256, MINW) void conv3x3_v12(
    const _Float16* __restrict__ xhi,
    const _Float16* __restrict__ xlo,
    const _Float16* __restrict__ wc,
    const _Float16* __restrict__ zbuf,
    const float* __restrict__ scl, const float* __restrict__ tb,
    _Float16* __restrict__ ohi, _Float16* __restrict__ olo,
    float* __restrict__ onchw)
{
    constexpr int K       = CIN * 9;
    constexpr int NCH     = K / 32;
    constexpr int WROWS   = 2 * COUT;
    constexpr int CHALVES = WROWS * 32;
    constexpr int WI      = WROWS / 64;
    constexpr int PI      = 2;
    constexpr int WOC     = COUT / 64;

    __shared__ __align__(16) _Float16 SP[128 * 64];
    __shared__ __align__(16) _Float16 SW[WROWS * 32];

    const int bid = blockIdx.x;
    const int swz = (bid & 7) * (gridDim.x >> 3) + (bid >> 3);
    const int b = swz / 25;
    const int pixBase = (swz - b * 25) * 128;
    const int bHW = b * HW;

    const int t = threadIdx.x, l = t & 63, w = t >> 6;

    const int cpix = (l & 7) ^ ((l >> 3) & 7);
    const int ppl = cpix >> 2, pq = cpix & 3;
    const _Float16* xsp = ppl ? xlo : xhi;
    int py[4], px[4];
    const _Float16* pbase[4];
#pragma unroll
    for (int i = 0; i < 4; ++i) {
        int p = w * 32 + i * 8 + (l >> 3);
        int pix = pixBase + p;
        py[i] = pix / 56; px[i] = pix - py[i] * 56;
        pbase[i] = xsp + (size_t)(bHW + pix) * CIN + pq * 8;
    }
    const _Float16* wbase = wc + ((size_t)(w * (WI * 16) + (l >> 2))) * 32 + (l & 3) * 8;

    const int wid = t >> 6;
    const int wp = wid & 1, wo = wid >> 1;
    const int lc = l & 31, lk = l >> 5;

    f32x16 acc[PI][WOC];
#pragma unroll
    for (int pi = 0; pi < PI; ++pi)
#pragma unroll
        for (int oi = 0; oi < WOC; ++oi) acc[pi][oi] = (f32x16)0.f;

    auto stage = [&](int ch) {
        int cg = ch / 9, r = ch - cg * 9;
        int ky = r / 3;
        int dy = ky - 1, dx = (r - ky * 3) - 1;
        int off = (dy * 56 + dx) * CIN + cg * 32;
#pragma unroll
        for (int i = 0; i < 4; ++i) {
            bool v = ((unsigned)(py[i] + dy) < 56u) && ((unsigned)(px[i] + dx) < 56u);
            const void* src = v ? (const void*)(pbase[i] + off) : (const void*)zbuf;
            g2l16(src, (void*)&SP[w * 2048 + i * 512]);
        }
        const _Float16* wsrc = wbase + (size_t)ch * CHALVES;
#pragma unroll
        for (int j = 0; j < WI; ++j)
            g2l16((const void*)(wsrc + j * 512), (void*)&SW[(w * WI + j) * 512]);
    };

    auto compute = [&]() {
#pragma unroll
        for (int ks = 0; ks < 2; ++ks) {
            half8 pb[PI][2];
#pragma unroll
            for (int pi = 0; pi < PI; ++pi) {
                int prw = wp * (PI * 32) + pi * 32 + lc;
                int key = prw & 7;
#pragma unroll
                for (int pl2 = 0; pl2 < 2; ++pl2) {
                    int c = pl2 * 4 + ks * 2 + lk;
                    pb[pi][pl2] = *(const half8*)&SP[prw * 64 + ((c ^ key) << 3)];
                }
            }
            half8 wa[WOC][2];
#pragma unroll
            for (int oi = 0; oi < WOC; ++oi)
#pragma unroll
                for (int pl2 = 0; pl2 < 2; ++pl2) {
                    int row = pl2 * COUT + wo * (WOC * 32) + oi * 32 + lc;
                    int c = ks * 2 + lk;
                    wa[oi][pl2] = *(const half8*)&SW[row * 32 + (c << 3)];
                }
#pragma unroll
            for (int pi = 0; pi < PI; ++pi)
#pragma unroll
                for (int oi = 0; oi < WOC; ++oi) {
                    acc[pi][oi] = __builtin_amdgcn_mfma_f32_32x32x16_f16(wa[oi][0], pb[pi][0], acc[pi][oi], 0, 0, 0);
                    acc[pi][oi] = __builtin_amdgcn_mfma_f32_32x32x16_f16(wa[oi][0], pb[pi][1], acc[pi][oi], 0, 0, 0);
                    acc[pi][oi] = __builtin_amdgcn_mfma_f32_32x32x16_f16(wa[oi][1], pb[pi][0], acc[pi][oi], 0, 0, 0);
                }
        }
    };

    for (int ch = 0; ch < NCH; ++ch) {
        stage(ch);
        __syncthreads();
        compute();
        __syncthreads();
    }

#pragma unroll
    for (int pi = 0; pi < PI; ++pi) {
        const int pix = pixBase + wp * (PI * 32) + pi * 32 + lc;
        if (pix < HW) {
#pragma unroll
            for (int oi = 0; oi < WOC; ++oi) {
#pragma unroll
                for (int g = 0; g < 4; ++g) {
                    const int oc0 = wo * (WOC * 32) + oi * 32 + 8 * g + 4 * lk;
                    f32x4 s4 = *(const f32x4*)(scl + oc0);
                    f32x4 t4 = *(const f32x4*)(tb + oc0);
                    if constexpr (NHWC_OUT) {
                        half4v hh, ll;
#pragma unroll
                        for (int m2 = 0; m2 < 4; ++m2) {
                            float val = fmaxf(acc[pi][oi][g * 4 + m2] * s4[m2] + t4[m2], 0.f);
                            _Float16 h = (_Float16)val;
                            hh[m2] = h;
                            ll[m2] = (_Float16)(val - (float)h);
                        }
                        size_t o = ((size_t)(bHW + pix)) * COUT + oc0;
                        *(half4v*)(ohi + o) = hh;
                        *(half4v*)(olo + o) = ll;
                    } else {
#pragma unroll
                        for (int m2 = 0; m2 < 4; ++m2) {
                            float val = fmaxf(acc[pi][oi][g * 4 + m2] * s4[m2] + t4[m2], 0.f);
                            onchw[((size_t)(b * COUT + oc0 + m2)) * HW + pix] = val;
                        }
                    }
                }
            }
        }
    }
}

// ---------------- conv1x1 (64 -> per-anchor 5) + decode (NCHW fp32 x2) ----------------
__global__ __launch_bounds__(256) void conv1x1_decode(
    const float* __restrict__ x2, const float* __restrict__ wo,
    const float* __restrict__ bo,
    float* __restrict__ boxes, float* __restrict__ scores)
{
    __shared__ float ws[64 * 56];
    for (int i = threadIdx.x; i < 54 * 64; i += 256) {
        int oc = i % 54, c = i / 54;
        ws[c * 56 + oc] = wo[oc * 64 + c];
    }
    __syncthreads();

    int u = blockIdx.x * 256 + threadIdx.x;
    int a = u % 9;
    int rest = u / 9;
    int quad = rest % 784;
    int b = rest / 784;
    int pix0 = quad * 4;
    int y = pix0 / 56;
    int x0 = pix0 - y * 56;

    const float* xb = x2 + (size_t)b * 64 * HW + pix0;
    float acc[5][4];
#pragma unroll
    for (int j = 0; j < 5; ++j)
#pragma unroll
        for (int p = 0; p < 4; ++p) acc[j][p] = 0.f;

#pragma unroll 8
    for (int c = 0; c < 64; ++c) {
        float4 xv = *(const float4*)(xb + c * HW);
#pragma unroll
        for (int j = 0; j < 5; ++j) {
            float w = ws[c * 56 + a * 6 + j];
            acc[j][0] += w * xv.x;
            acc[j][1] += w * xv.y;
            acc[j][2] += w * xv.z;
            acc[j][3] += w * xv.w;
        }
    }

    int si = a / 3, ri = a - si * 3;
    float sv = (float)(32 << si);
    float rv = 0.5f * (float)(1 << ri);
    float aw = (sv * rv) / 224.f;
    float ah = (sv / rv) / 224.f;
    float bo0 = bo[a * 6 + 0], bo1 = bo[a * 6 + 1], bo2 = bo[a * 6 + 2];
    float bo3 = bo[a * 6 + 3], bo4 = bo[a * 6 + 4];

#pragma unroll
    for (int p = 0; p < 4; ++p) {
        float p0 = acc[0][p] + bo0;
        float p1 = acc[1][p] + bo1;
        float p2 = acc[2][p] + bo2;
        float p3 = acc[3][p] + bo3;
        float p4 = acc[4][p] + bo4;
        float sx = 1.f / (1.f + expf(-p0));
        float sy = 1.f / (1.f + expf(-p1));
        float pxc = (sx + (float)(x0 + p)) / 56.f;
        float pyc = (sy + (float)y) / 56.f;
        float pw = expf(p2) * aw;
        float ph = expf(p3) * ah;
        float sc = 1.f / (1.f + expf(-p4));
        int n = (y * 56 + x0 + p) * 9 + a;
        float4 bx; bx.x = pxc; bx.y = pyc; bx.z = pw; bx.w = ph;
        *(float4*)&boxes[((size_t)b * NCAND + n) * 4] = bx;
        scores[(size_t)b * NCAND + n] = sc;
    }
}

// ---------------- top-K v3: 3 radix rounds (11/10/10 bits), parallel scan ----------------
__device__ __forceinline__ unsigned fkey(float f) {
    unsigned u = __float_as_uint(f);
    return (u & 0x80000000u) ? ~u : (u | 0x80000000u);
}

__global__ __launch_bounds__(1024) void topk_select(
    const float* __restrict__ scores, const float* __restrict__ boxes,
    float* __restrict__ cbox, float* __restrict__ csc, int* __restrict__ cidx)
{
    const int b = blockIdx.x, t = threadIdx.x;
    const float* sp = scores + (size_t)b * NCAND;
    const int lane = t & 63, w = t >> 6;

    __shared__ unsigned hist[2048];
    __shared__ unsigned gsum[64];
    __shared__ unsigned wsum[16];
    __shared__ unsigned s_sel, s_need, s_tot0, s_tot1;

    unsigned prefix = 0x80000000u, maskSo = 0x80000000u;
    int need = KSEL;

    for (int round = 0; round < 3; ++round) {
        const int shift = (round == 0) ? 20 : (round == 1 ? 10 : 0);
        const unsigned bmask = (round == 0) ? 2047u : 1023u;
        const int ngroups = (round == 0) ? 64 : 32;

        hist[t] = 0;
        if (round == 0) hist[t + 1024] = 0;
        __syncthreads();
        for (int i = t; i < NCAND; i += 1024) {
            unsigned u = fkey(sp[i]);
            if ((u & maskSo) == prefix) atomicAdd(&hist[(u >> shift) & bmask], 1u);
        }
        __syncthreads();
        if (t < ngroups) {
            unsigned s = 0;
#pragma unroll 8
            for (int k = 0; k < 32; ++k) s += hist[t * 32 + k];
            gsum[t] = s;
        }
        __syncthreads();
        if (t == 0) {
            int rem = need;
            int g = ngroups - 1;
            for (;; --g) {
                if ((int)gsum[g] >= rem || g == 0) break;
                rem -= (int)gsum[g];
            }
            unsigned sel = (unsigned)(g * 32);
            for (int v = g * 32 + 31; v >= g * 32; --v) {
                int c = (int)hist[v];
                if (c >= rem || v == g * 32) { sel = (unsigned)v; break; }
                rem -= c;
            }
            s_sel = sel; s_need = (unsigned)rem;
        }
        __syncthreads();
        prefix |= (s_sel << shift);
        maskSo |= (bmask << shift);
        need = (int)s_need;
        __syncthreads();
    }

    const unsigned cutoff = prefix;
    const unsigned needT = (unsigned)need;
    unsigned outBase = 0, tieBase = 0;
    const unsigned long long mlt = (1ull << lane) - 1ull;

    for (int c0 = 0; c0 < NCAND; c0 += 1024) {
        int i = c0 + t;
        bool valid = i < NCAND;
        float sc = valid ? sp[i] : 0.f;
        unsigned u = valid ? fkey(sc) : 0u;
        bool gt = valid && (u > cutoff);
        bool eq = valid && (u == cutoff);

        unsigned long long balE = __ballot(eq);
        unsigned lpE = (unsigned)__popcll(balE & mlt);
        if (lane == 0) wsum[w] = (unsigned)__popcll(balE);
        __syncthreads();
        if (t == 0) {
            unsigned run = 0;
            for (int k = 0; k < 16; ++k) { unsigned x = wsum[k]; wsum[k] = run; run += x; }
            s_tot1 = run;
        }
        __syncthreads();
        unsigned tieRank = tieBase + wsum[w] + lpE;
        bool take = gt || (eq && tieRank < needT);
        __syncthreads();

        unsigned long long balT = __ballot(take);
        unsigned lpT = (unsigned)__popcll(balT & mlt);
        if (lane == 0) wsum[w] = (unsigned)__popcll(balT);
        __syncthreads();
        if (t == 0) {
            unsigned run = 0;
            for (int k = 0; k < 16; ++k) { unsigned x = wsum[k]; wsum[k] = run; run += x; }
            s_tot0 = run;
        }
        __syncthreads();
        unsigned pos = outBase + wsum[w] + lpT;
        if (take) {
            float4 bx = *(const float4*)&boxes[((size_t)b * NCAND + i) * 4];
            *(float4*)&cbox[((size_t)b * KSEL + pos) * 4] = bx;
            csc[(size_t)b * KSEL + pos] = sc;
            cidx[(size_t)b * KSEL + pos] = i;
        }
        tieBase += s_tot1;
        outBase += s_tot0;
        __syncthreads();
    }
}

// ---------------- NMS: one wave per image, all candidates in registers ----------------
__global__ __launch_bounds__(64) void nms_wave(
    const float* __restrict__ cbox, const float* __restrict__ csc,
    const int* __restrict__ cidx, float* __restrict__ out)
{
    const int b = blockIdx.x, l = threadIdx.x;
    float cx[16], cy[16], w_[16], h_[16], s[16];
    int id[16];
#pragma unroll
    for (int j = 0; j < 16; ++j) {
        int ci = (b << 10) + (j << 6) + l;
        float4 bb = *(const float4*)&cbox[(size_t)ci * 4];
        float sc = csc[ci];
        cx[j] = bb.x; cy[j] = bb.y; w_[j] = bb.z; h_[j] = bb.w;
        s[j] = sc > 0.3f ? sc : -1.f;
        id[j] = cidx[ci];
    }
    float* ob = out + (size_t)b * MAXDET * 4;

    for (int it = 0; it < MAXDET; ++it) {
        float bs = s[0]; int bi = id[0];
        float bcx = cx[0], bcy = cy[0], bw = w_[0], bh = h_[0];
#pragma unroll
        for (int j = 1; j < 16; ++j) {
            bool tk = (s[j] > bs) || (s[j] == bs && id[j] < bi);
            if (tk) { bs = s[j]; bi = id[j]; bcx = cx[j]; bcy = cy[j]; bw = w_[j]; bh = h_[j]; }
        }
#pragma unroll
        for (int m2 = 1; m2 < 64; m2 <<= 1) {
            float os = __shfl_xor(bs, m2); int oi = __shfl_xor(bi, m2);
            float ox = __shfl_xor(bcx, m2), oy = __shfl_xor(bcy, m2);
            float ow = __shfl_xor(bw, m2), oh2 = __shfl_xor(bh, m2);
            bool tk = (os > bs) || (os == bs && oi < bi);
            if (tk) { bs = os; bi = oi; bcx = ox; bcy = oy; bw = ow; bh = oh2; }
        }
        if (bs <= 0.f) {
            for (int q = it * 4 + l; q < MAXDET * 4; q += 64) ob[q] = 0.f;
            break;
        }
        if (l == 0) {
            float4 o; o.x = bcx; o.y = bcy; o.z = bw; o.w = bh;
            *(float4*)&ob[it * 4] = o;
        }
        float wx1 = bcx - bw / 2.f, wy1 = bcy - bh / 2.f;
        float wx2 = bcx + bw / 2.f, wy2 = bcy + bh / 2.f;
        float war = (wx2 - wx1) * (wy2 - wy1);
#pragma unroll
        for (int j = 0; j < 16; ++j) {
            float jx1 = cx[j] - w_[j] / 2.f, jy1 = cy[j] - h_[j] / 2.f;
            float jx2 = cx[j] + w_[j] / 2.f, jy2 = cy[j] + h_[j] / 2.f;
            float iw = fminf(wx2, jx2) - fmaxf(wx1, jx1); iw = fmaxf(iw, 0.f);
            float ih = fminf(wy2, jy2) - fmaxf(wy1, jy1); ih = fmaxf(ih, 0.f);
            float inter = iw * ih;
            float jar = (jx2 - jx1) * (jy2 - jy1);
            float uni = war + jar - inter;
            if (inter / (uni + 1e-16f) > 0.2f) s[j] = -1.f;
        }
    }
}

// ---------------- host launcher ----------------
extern "C" void kernel_launch(void* const* d_in, const int* in_sizes, int n_in,
                              void* d_out, int out_size, void* d_ws, size_t ws_size,
                              hipStream_t stream)
{
    const float* features = (const float*)d_in[0];
    const float* w1 = (const float*)d_in[1];
    const float* b1 = (const float*)d_in[2];
    const float* g1 = (const float*)d_in[3];
    const float* be1 = (const float*)d_in[4];
    const float* m1 = (const float*)d_in[5];
    const float* v1 = (const float*)d_in[6];
    const float* w2 = (const float*)d_in[7];
    const float* b2 = (const float*)d_in[8];
    const float* g2 = (const float*)d_in[9];
    const float* be2 = (const float*)d_in[10];
    const float* m2 = (const float*)d_in[11];
    const float* v2 = (const float*)d_in[12];
    const float* wo = (const float*)d_in[13];
    const float* bo = (const float*)d_in[14];

    char* ws = (char*)d_ws;
    size_t off = 0;
    auto alloc = [&](size_t bytes) {
        char* p = ws + off;
        off += (bytes + 255) / 256 * 256;
        return p;
    };

    _Float16* zbuf = (_Float16*)alloc(256);
    _Float16* w1c = (_Float16*)alloc((size_t)2 * C1 * 2304 * 2);
    _Float16* w2c = (_Float16*)alloc((size_t)2 * C2 * 1152 * 2);
    float* scl1 = (float*)alloc(C1 * 4);
    float* tb1  = (float*)alloc(C1 * 4);
    float* scl2 = (float*)alloc(C2 * 4);
    float* tb2  = (float*)alloc(C2 * 4);

    // Region B: fhi/flo (dead after conv1), then reused for x2/boxes/scores
    const size_t planeF = (size_t)BB * HW * C0 * 2;    // 51,380,224
    char* regB = alloc(2 * planeF);
    _Float16* fhi = (_Float16*)regB;
    _Float16* flo = (_Float16*)(regB + planeF);

    // Region C: x1 hi/lo (dead after conv2), then reused for cbox/csc/cidx
    const size_t planeX1 = (size_t)BB * HW * C1 * 2;   // 25,690,112
    char* regC = alloc(2 * planeX1);
    _Float16* x1hi = (_Float16*)regC;
    _Float16* x1lo = (_Float16*)(regC + planeX1);

    // aliases into region B (valid after conv1 completes)
    float* x2     = (float*)regB;
    float* boxes  = (float*)(regB + 25690112);
    float* scores = (float*)(regB + 25690112 + 14450688);
    // aliases into region C (valid after conv2 completes)
    float* cbox = (float*)regC;
    float* csc  = (float*)(regC + 524288);
    int*   cidx = (int*)(regC + 524288 + 131072);

    hipMemsetAsync(zbuf, 0, 256, stream);
    bn_prep2<<<1, 256, 0, stream>>>(g1, be1, m1, v1, b1, g2, be2, m2, v2, b2,
                                    scl1, tb1, scl2, tb2);
    {
        int total = 2 * C1 * 2304 + 2 * C2 * 1152;
        reorder_w_both<<<(total + 255) / 256, 256, 0, stream>>>(w1, w1c, w2, w2c);
    }

    nchw_to_nhwc_split<<<dim3(49, 4, BB), 256, 0, stream>>>(features, fhi, flo);

    conv3x3_v18<C0, C1, true><<<800, 256, 0, stream>>>(
        fhi, flo, w1c, zbuf, scl1, tb1, x1hi, x1lo, nullptr);
    conv3x3_v12<C1, C2, 4, false><<<800, 256, 0, stream>>>(
        x1hi, x1lo, w2c, zbuf, scl2, tb2, nullptr, nullptr, x2);

    conv1x1_decode<<<(BB * 784 * NA) / 256, 256, 0, stream>>>(x2, wo, bo, boxes, scores);

    topk_select<<<BB, 1024, 0, stream>>>(scores, boxes, cbox, csc, cidx);
    nms_wave<<<BB, 64, 0, stream>>>(cbox, csc, cidx, (float*)d_out);
}